// Round 1
// baseline (1322.074 us; speedup 1.0000x reference)
//
#include <hip/hip_runtime.h>
#include <hip/hip_bf16.h>

#define HID 256
#define NC  19

// ---------------- CSR build ----------------

__global__ void hist_kernel(const int* __restrict__ edst, int E, int* __restrict__ deg) {
    int i = blockIdx.x * blockDim.x + threadIdx.x;
    if (i < E) atomicAdd(&deg[edst[i]], 1);
}

__global__ void scanA_kernel(const int* __restrict__ deg, int* __restrict__ offs,
                             int* __restrict__ bsums, int n) {
    __shared__ int s[256];
    int i = blockIdx.x * 256 + threadIdx.x;
    int v = (i < n) ? deg[i] : 0;
    s[threadIdx.x] = v;
    __syncthreads();
    for (int d = 1; d < 256; d <<= 1) {
        int t = (threadIdx.x >= d) ? s[threadIdx.x - d] : 0;
        __syncthreads();
        s[threadIdx.x] += t;
        __syncthreads();
    }
    if (i < n) offs[i] = s[threadIdx.x] - v;          // exclusive within block
    if (threadIdx.x == 255) bsums[blockIdx.x] = s[255]; // block total
}

__global__ void scanB_kernel(int* __restrict__ bsums, int nb) {
    __shared__ int s[256];
    int v = (threadIdx.x < nb) ? bsums[threadIdx.x] : 0;
    s[threadIdx.x] = v;
    __syncthreads();
    for (int d = 1; d < 256; d <<= 1) {
        int t = (threadIdx.x >= d) ? s[threadIdx.x - d] : 0;
        __syncthreads();
        s[threadIdx.x] += t;
        __syncthreads();
    }
    if (threadIdx.x < nb) bsums[threadIdx.x] = s[threadIdx.x] - v; // exclusive
}

__global__ void scanC_kernel(int* __restrict__ offs, const int* __restrict__ bsums,
                             int* __restrict__ cursor, int n) {
    int i = blockIdx.x * 256 + threadIdx.x;
    if (i < n) {
        int o = offs[i] + bsums[blockIdx.x];
        offs[i] = o;
        cursor[i] = o;
    }
}

__global__ void scatter_kernel(const int* __restrict__ esrc, const int* __restrict__ edst,
                               int E, int* __restrict__ cursor, int* __restrict__ eidx) {
    int i = blockIdx.x * blockDim.x + threadIdx.x;
    if (i < E) {
        int d = edst[i];
        int pos = atomicAdd(&cursor[d], 1);
        eidx[pos] = esrc[i];
    }
}

// ---------------- mean aggregation (wave per dst row) ----------------
// 256 feats = 64 lanes x float4; lane l owns floats [4l,4l+4)
__global__ void aggregate_kernel(const int* __restrict__ eidx, const int* __restrict__ offs,
                                 const int* __restrict__ deg, const float* __restrict__ hsrc,
                                 float* __restrict__ mean, int ndst) {
    int d = blockIdx.x * 4 + (threadIdx.x >> 6);
    int lane = threadIdx.x & 63;
    if (d >= ndst) return;
    int start = offs[d];
    int cnt = deg[d];
    float4 acc = make_float4(0.f, 0.f, 0.f, 0.f);
    for (int e = 0; e < cnt; ++e) {
        int s = eidx[start + e];
        float4 v = *reinterpret_cast<const float4*>(hsrc + (size_t)s * HID + lane * 4);
        acc.x += v.x; acc.y += v.y; acc.z += v.z; acc.w += v.w;
    }
    float inv = 1.0f / (float)(cnt > 1 ? cnt : 1);
    acc.x *= inv; acc.y *= inv; acc.z *= inv; acc.w *= inv;
    *reinterpret_cast<float4*>(mean + (size_t)d * HID + lane * 4) = acc;
}

// ---------------- fused GEMM: out = act(hdst @ Wself + mean @ Wneigh + b) --------
// Treated as [hdst | mean] (M x 512) @ [Wself; Wneigh] (512 x 256).
// BM=128, BN=64, BK=16, 256 threads, each thread computes 8x4.
template <bool RELU>
__global__ __launch_bounds__(256) void sage_gemm(
    const float* __restrict__ hdst, const float* __restrict__ mean,
    const float* __restrict__ Wself, const float* __restrict__ Wneigh,
    const float* __restrict__ bias, float* __restrict__ out, int M) {
    __shared__ float As[16][128];
    __shared__ float Bs[16][64];
    const int tid = threadIdx.x;
    const int m0 = blockIdx.x * 128;
    const int c0 = blockIdx.y * 64;

    const int aRow = tid >> 1;          // 0..127
    const int aK   = (tid & 1) * 8;     // 0 or 8
    const int bK   = tid >> 4;          // 0..15
    const int bN   = (tid & 15) * 4;    // 0..60
    const int tx   = tid & 15;          // col group
    const int ty   = tid >> 4;          // row group

    const float4* As4 = reinterpret_cast<const float4*>(&As[0][0]);
    const float4* Bs4 = reinterpret_cast<const float4*>(&Bs[0][0]);

    float acc[8][4];
#pragma unroll
    for (int i = 0; i < 8; ++i)
#pragma unroll
        for (int j = 0; j < 4; ++j) acc[i][j] = 0.f;

    for (int kt = 0; kt < 32; ++kt) {
        const int k = kt * 16;
        // load A slice (128 x 16) : from hdst for k<256, from mean for k>=256
        const float* Abase = (k < 256)
            ? hdst + (size_t)(m0 + aRow) * HID + (k + aK)
            : mean + (size_t)(m0 + aRow) * HID + (k - 256 + aK);
        float4 av0 = *reinterpret_cast<const float4*>(Abase);
        float4 av1 = *reinterpret_cast<const float4*>(Abase + 4);
        // load B slice (16 x 64)
        const float* Bbase = (k < 256)
            ? Wself  + (size_t)(k + bK) * HID + (c0 + bN)
            : Wneigh + (size_t)(k - 256 + bK) * HID + (c0 + bN);
        float4 bv = *reinterpret_cast<const float4*>(Bbase);

        __syncthreads(); // previous iteration's reads done
        As[aK + 0][aRow] = av0.x; As[aK + 1][aRow] = av0.y;
        As[aK + 2][aRow] = av0.z; As[aK + 3][aRow] = av0.w;
        As[aK + 4][aRow] = av1.x; As[aK + 5][aRow] = av1.y;
        As[aK + 6][aRow] = av1.z; As[aK + 7][aRow] = av1.w;
        *reinterpret_cast<float4*>(&Bs[bK][bN]) = bv;
        __syncthreads();

#pragma unroll
        for (int kk = 0; kk < 16; ++kk) {
            float4 a0 = As4[kk * 32 + ty * 2];
            float4 a1 = As4[kk * 32 + ty * 2 + 1];
            float4 b  = Bs4[kk * 16 + tx];
            float ar[8] = {a0.x, a0.y, a0.z, a0.w, a1.x, a1.y, a1.z, a1.w};
            float br[4] = {b.x, b.y, b.z, b.w};
#pragma unroll
            for (int i = 0; i < 8; ++i)
#pragma unroll
                for (int j = 0; j < 4; ++j) acc[i][j] += ar[i] * br[j];
        }
    }

    float4 b4 = *reinterpret_cast<const float4*>(bias + c0 + tx * 4);
    float bb[4] = {b4.x, b4.y, b4.z, b4.w};
#pragma unroll
    for (int i = 0; i < 8; ++i) {
        float4 o;
        float* op = &o.x;
#pragma unroll
        for (int j = 0; j < 4; ++j) {
            float v = acc[i][j] + bb[j];
            if (RELU) v = fmaxf(v, 0.f);
            op[j] = v;
        }
        *reinterpret_cast<float4*>(out + (size_t)(m0 + ty * 8 + i) * HID + c0 + tx * 4) = o;
    }
}

// ---------------- final layer: M=512, K=2x256, N=19, no relu ----------------
__global__ void out_gemm(const float* __restrict__ hdst, const float* __restrict__ mean,
                         const float* __restrict__ Wself, const float* __restrict__ Wneigh,
                         const float* __restrict__ bias, float* __restrict__ out) {
    int r = blockIdx.x;       // 0..511
    int lane = threadIdx.x;   // 64 lanes, 0..18 active
    if (lane >= NC) return;
    const float* hr = hdst + (size_t)r * HID;
    const float* mr = mean + (size_t)r * HID;
    float s0 = 0.f, s1 = 0.f, s2 = 0.f, s3 = 0.f;
    for (int k = 0; k < HID; k += 4) {
        s0 = fmaf(hr[k],     Wself[(k)     * NC + lane], s0);
        s1 = fmaf(hr[k + 1], Wself[(k + 1) * NC + lane], s1);
        s2 = fmaf(hr[k + 2], Wself[(k + 2) * NC + lane], s2);
        s3 = fmaf(hr[k + 3], Wself[(k + 3) * NC + lane], s3);
    }
    for (int k = 0; k < HID; k += 4) {
        s0 = fmaf(mr[k],     Wneigh[(k)     * NC + lane], s0);
        s1 = fmaf(mr[k + 1], Wneigh[(k + 1) * NC + lane], s1);
        s2 = fmaf(mr[k + 2], Wneigh[(k + 2) * NC + lane], s2);
        s3 = fmaf(mr[k + 3], Wneigh[(k + 3) * NC + lane], s3);
    }
    out[r * NC + lane] = s0 + s1 + s2 + s3 + bias[lane];
}

// ---------------- launcher ----------------

extern "C" void kernel_launch(void* const* d_in, const int* in_sizes, int n_in,
                              void* d_out, int out_size, void* d_ws, size_t ws_size,
                              hipStream_t stream) {
    const float* x     = (const float*)d_in[0];
    const int* esrc0   = (const int*)d_in[1];
    const int* edst0   = (const int*)d_in[2];
    const int* esrc1   = (const int*)d_in[3];
    const int* edst1   = (const int*)d_in[4];
    const int* esrc2   = (const int*)d_in[5];
    const int* edst2   = (const int*)d_in[6];
    const float* Ws0   = (const float*)d_in[7];
    const float* Wn0   = (const float*)d_in[8];
    const float* b0    = (const float*)d_in[9];
    const float* Ws1   = (const float*)d_in[10];
    const float* Wn1   = (const float*)d_in[11];
    const float* b1    = (const float*)d_in[12];
    const float* Ws2   = (const float*)d_in[13];
    const float* Wn2   = (const float*)d_in[14];
    const float* b2    = (const float*)d_in[15];

    const int NDST0 = 61952, NDST1 = 5632, NDST2 = 512;
    const int E0 = in_sizes[1], E1 = in_sizes[3], E2 = in_sizes[5];

    char* ws = (char*)d_ws;
    size_t off = 0;
    auto alloc = [&](size_t bytes) -> void* {
        void* p = ws + off;
        off += (bytes + 255) & ~(size_t)255;
        return p;
    };
    float* mean0 = (float*)alloc((size_t)NDST0 * HID * 4);
    float* h1    = (float*)alloc((size_t)NDST0 * HID * 4);
    float* mean1 = (float*)alloc((size_t)NDST1 * HID * 4);
    float* h2    = (float*)alloc((size_t)NDST1 * HID * 4);
    float* mean2 = (float*)alloc((size_t)NDST2 * HID * 4);
    int* eidx    = (int*)alloc((size_t)E0 * 4);
    int* deg     = (int*)alloc((size_t)NDST0 * 4);
    int* offs    = (int*)alloc((size_t)NDST0 * 4);
    int* cursor  = (int*)alloc((size_t)NDST0 * 4);
    int* bsums   = (int*)alloc(1024);

    auto run_csr_mean = [&](const float* hsrc, const int* esrc, const int* edst,
                            int E, int ndst, float* mean) {
        hipMemsetAsync(deg, 0, (size_t)ndst * 4, stream);
        hist_kernel<<<dim3((E + 255) / 256), dim3(256), 0, stream>>>(edst, E, deg);
        int nb = (ndst + 255) / 256;
        scanA_kernel<<<dim3(nb), dim3(256), 0, stream>>>(deg, offs, bsums, ndst);
        scanB_kernel<<<dim3(1), dim3(256), 0, stream>>>(bsums, nb);
        scanC_kernel<<<dim3(nb), dim3(256), 0, stream>>>(offs, bsums, cursor, ndst);
        scatter_kernel<<<dim3((E + 255) / 256), dim3(256), 0, stream>>>(esrc, edst, E, cursor, eidx);
        aggregate_kernel<<<dim3((ndst + 3) / 4), dim3(256), 0, stream>>>(eidx, offs, deg, hsrc, mean, ndst);
    };

    // Layer 0: x -> h1 (relu)
    run_csr_mean(x, esrc0, edst0, E0, NDST0, mean0);
    sage_gemm<true><<<dim3(NDST0 / 128, 4), dim3(256), 0, stream>>>(x, mean0, Ws0, Wn0, b0, h1, NDST0);

    // Layer 1: h1 -> h2 (relu)
    run_csr_mean(h1, esrc1, edst1, E1, NDST1, mean1);
    sage_gemm<true><<<dim3(NDST1 / 128, 4), dim3(256), 0, stream>>>(h1, mean1, Ws1, Wn1, b1, h2, NDST1);

    // Layer 2: h2 -> out (512 x 19, no relu)
    run_csr_mean(h2, esrc2, edst2, E2, NDST2, mean2);
    out_gemm<<<dim3(512), dim3(64), 0, stream>>>(h2, mean2, Ws2, Wn2, b2, (float*)d_out);
}